// Round 19
// baseline (233.218 us; speedup 1.0000x reference)
//
#include <hip/hip_runtime.h>
#include <hip/hip_bf16.h>
#include <math.h>

typedef short bf16x8 __attribute__((ext_vector_type(8)));
typedef float f32x4 __attribute__((ext_vector_type(4)));
typedef unsigned int u32;

#define B_DIM 8192
#define H_DIM 1024
#define NPATH 256
#define NSTEP 50

__device__ __forceinline__ void gld_lds16(const void* g, void* lds) {
  __builtin_amdgcn_global_load_lds(
      (const __attribute__((address_space(1))) u32*)g,
      (__attribute__((address_space(3))) u32*)lds, 16, 0, 0);
}

__device__ __forceinline__ void cast4(const float* in, __hip_bfloat16* out, int i) {
  float4 v = ((const float4*)in)[i];
  union { __hip_bfloat16 h[4]; short4 s; } u;
  u.h[0] = __float2bfloat16(v.x);
  u.h[1] = __float2bfloat16(v.y);
  u.h[2] = __float2bfloat16(v.z);
  u.h[3] = __float2bfloat16(v.w);
  ((short4*)out)[i] = u.s;
}

// ---------------- fused prep: pure data movement ----------------
// [0,8192) cast x ; [8192,11264) transpose W_in/W_hid/W_out ; [11264,11520) W_agg^T
__global__ __launch_bounds__(256) void prep_kernel(
    const float* __restrict__ x, const float* __restrict__ W_in,
    const float* __restrict__ W_hid, const float* __restrict__ W_out,
    const float* __restrict__ W_agg,
    __hip_bfloat16* __restrict__ xb, __hip_bfloat16* __restrict__ wtin,
    __hip_bfloat16* __restrict__ wthid, __hip_bfloat16* __restrict__ wtout,
    __hip_bfloat16* __restrict__ wtagg) {
  __shared__ float t[32][33];
  int bid = blockIdx.x, tid = threadIdx.x;
  if (bid < 8192) {
    cast4(x, xb, bid * 256 + tid);
    return;
  }
  int job = bid - 8192;
  const float* W; __hip_bfloat16* Wt; int R, C;
  if (job < 1024)      { W = W_in;  Wt = wtin;  R = 1024; C = 1024; }
  else if (job < 2048) { W = W_hid; Wt = wthid; R = 1024; C = 1024; job -= 1024; }
  else if (job < 3072) { W = W_out; Wt = wtout; R = 1024; C = 1024; job -= 2048; }
  else                 { W = W_agg; Wt = wtagg; R = 256;  C = 1024; job -= 3072; }
  int nTx = C / 32;
  int tX = job % nTx, tY = job / nTx;
  int tx = tid & 31, r4 = tid >> 5;
#pragma unroll
  for (int i = 0; i < 4; ++i) {
    int ty = r4 * 4 + i;
    t[ty][tx] = W[(size_t)(tY * 32 + ty) * C + tX * 32 + tx];
  }
  __syncthreads();
#pragma unroll
  for (int i = 0; i < 4; ++i) {
    int ty = r4 * 4 + i;
    Wt[(size_t)(tX * 32 + ty) * R + tY * 32 + tx] = __float2bfloat16(t[tx][ty]);
  }
}

// ------------- fused feedback + endpoints: per block = 4 batch rows -------------
__global__ __launch_bounds__(256) void fb_end_kernel(
    const __hip_bfloat16* __restrict__ h2b, const float* __restrict__ Wfb,
    const float* __restrict__ bfb, const float* __restrict__ ns,
    __hip_bfloat16* __restrict__ eb, float DI, float SQDT) {
  __shared__ float fv[4];
  int wid = threadIdx.x >> 6, lane = threadIdx.x & 63;
  int row = blockIdx.x * 4 + wid;
  const __hip_bfloat16* hrow = h2b + (size_t)row * H_DIM;
  float s = 0.f;
#pragma unroll
  for (int i = lane; i < H_DIM; i += 64) s += __bfloat162float(hrow[i]) * Wfb[i];
#pragma unroll
  for (int off = 32; off > 0; off >>= 1) s += __shfl_down(s, off);
  if (lane == 0) fv[wid] = 1.0f / (1.0f + expf(-(s + bfb[0])));
  __syncthreads();
#pragma unroll
  for (int w = 0; w < 4; ++w) {
    size_t i = (size_t)(blockIdx.x * 4 + w) * NPATH + threadIdx.x;
    eb[i] = __float2bfloat16(fv[w] * DI + SQDT * ns[i]);
  }
}

// -------- trunk stage: group-of-8 interleave, 3:1 GEMM:noise block ratio -------
// grid 768 = 96 groups of 8. group%3==0 -> noise (32 groups = 256 blocks);
// else -> GEMM (64 groups = 512 tiles). Per-CU mix ~2 GEMM + 1 noise block
// (m114 overlap). vs R17's 1:1: GEMM gets ~2/3 of CUs (was CU-starved at 1/2);
// noise at 256 blocks still has ~13 outstanding loads/thread = full BW share.
// GEMM tile decode (XCD-local A panels): g_i = (group%3==1) ? (group/3)*2
// : (group/3)*2+1 ; bm = (g_i>>3)*8 + (bid&7), bn = g_i&7  (bijective).
__global__ __launch_bounds__(256) void stage_kernel(
    const __hip_bfloat16* __restrict__ A, const __hip_bfloat16* __restrict__ Bt,
    const float* __restrict__ bias, __hip_bfloat16* __restrict__ out,
    const float* __restrict__ noise, float* __restrict__ ns,
    int rowStart, int rowCount) {
  __shared__ __hip_bfloat16 As[128 * 64];
  __shared__ __hip_bfloat16 Bs[128 * 64];
  const int bid = blockIdx.x;
  const int group = bid >> 3, l = bid & 7;
  const int gm = group % 3;
  if (gm == 0) {
    int j = (group / 3) * 8 + l;  // 256 noise blocks, grid-stride
    for (int r = j * 256 + threadIdx.x; r < rowCount; r += 256 * 256) {
      const float2* p = (const float2*)(noise + (size_t)(rowStart + r) * NSTEP);
      float s = 0.f;
#pragma unroll
      for (int i = 0; i < NSTEP / 2; ++i) { float2 v = p[i]; s += v.x + v.y; }
      ns[rowStart + r] = s;
    }
    return;
  }
  const int g_i = (group / 3) * 2 + (gm - 1);  // 0..63
  const int bm = (g_i >> 3) * 8 + l;           // XCD-local A panels
  const int bn = g_i & 7;
  const int tid = threadIdx.x;
  const int lane = tid & 63, wid = tid >> 6;
  const int wr = wid >> 1, wc = wid & 1;
  const int frow = lane & 15, kgrp = lane >> 4;

  f32x4 acc[4][4];
#pragma unroll
  for (int m = 0; m < 4; ++m)
#pragma unroll
    for (int n = 0; n < 4; ++n) acc[m][n] = (f32x4){0.f, 0.f, 0.f, 0.f};

  for (int kt = 0; kt < H_DIM; kt += 64) {
#pragma unroll
    for (int r = 0; r < 4; ++r) {
      int c = r * 256 + tid;
      int row = c >> 3, cc = c & 7;
      gld_lds16((const char*)(A + (size_t)(bm * 128 + row) * H_DIM + kt) + cc * 16,
                (char*)As + c * 16);
      gld_lds16((const char*)(Bt + (size_t)(bn * 128 + row) * H_DIM + kt) + cc * 16,
                (char*)Bs + c * 16);
    }
    __syncthreads();
#pragma unroll
    for (int kk = 0; kk < 64; kk += 32) {
      bf16x8 af[4], bfr[4];
#pragma unroll
      for (int m = 0; m < 4; ++m)
        af[m] = *(const bf16x8*)(As + (wr * 64 + m * 16 + frow) * 64 + kk + kgrp * 8);
#pragma unroll
      for (int n = 0; n < 4; ++n)
        bfr[n] = *(const bf16x8*)(Bs + (wc * 64 + n * 16 + frow) * 64 + kk + kgrp * 8);
#pragma unroll
      for (int m = 0; m < 4; ++m)
#pragma unroll
        for (int n = 0; n < 4; ++n)
          acc[m][n] = __builtin_amdgcn_mfma_f32_16x16x32_bf16(af[m], bfr[n], acc[m][n], 0, 0, 0);
    }
    __syncthreads();
  }

  const int r0 = bm * 128 + wr * 64;
  const int c0 = bn * 128 + wc * 64;
#pragma unroll
  for (int n = 0; n < 4; ++n) {
    int col = c0 + n * 16 + frow;
    float bv = bias[col];
#pragma unroll
    for (int m = 0; m < 4; ++m)
#pragma unroll
      for (int j = 0; j < 4; ++j) {
        int row = r0 + m * 16 + kgrp * 4 + j;
        out[(size_t)row * H_DIM + col] = __float2bfloat16(fmaxf(acc[m][n][j] + bv, 0.f));
      }
  }
}

// ---------------- 256x128-tile core for bicep/final (counted-vmcnt dbuf) -------
// BM=256, BN=128, BK=64, 8 waves, pre-swizzled-source T2 + XCD bijective remap.
// t==0 waits vmcnt(6) (stage(0) only), keeping the t=1 prefetch in flight.
// MODE 2: +bias+extra->bf16 ; MODE 3: fp32.
template <int MODE>
__global__ __launch_bounds__(512) void gemm8(
    const __hip_bfloat16* __restrict__ A, const __hip_bfloat16* __restrict__ Bt,
    const float* __restrict__ bias, const __hip_bfloat16* __restrict__ extra,
    void* __restrict__ out, int N, int K, int nGemm) {
  constexpr int SMHALF = (256 + 128) * 64 * 2;
  __shared__ char smem[2 * SMHALF];

  const int tid = threadIdx.x;
  const int lane = tid & 63, wid = tid >> 6;
  const int wm = wid >> 2, wn = wid & 3;
  const int frow = lane & 15, kgrp = lane >> 4;
  const int cpx = nGemm >> 3;
  const int gb = (blockIdx.x & 7) * cpx + (blockIdx.x >> 3);  // XCD remap
  const int gx = N / 128;
  const int bm = gb / gx, bn = gb % gx;
  const size_t arow0 = (size_t)(bm * 256) * K;
  const size_t brow0 = (size_t)(bn * 128) * K;

  auto stage = [&](int kt, int d) {
    char* dst = smem + d * SMHALF;
#pragma unroll
    for (int j = 0; j < 6; ++j) {
      int c = j * 512 + tid;
      if (j < 4) {  // A tile: 256x64
        int row = c >> 3, cb = (c & 7) * 16;
        int col = (cb ^ ((row & 7) << 4)) >> 1;
        gld_lds16((const void*)(A + arow0 + (size_t)row * K + kt + col), dst + c * 16);
      } else {      // B tile: 128x64
        int cB = c - 2048;
        int row = cB >> 3, cb = (cB & 7) * 16;
        int col = (cb ^ ((row & 7) << 4)) >> 1;
        gld_lds16((const void*)(Bt + brow0 + (size_t)row * K + kt + col), dst + 32768 + cB * 16);
      }
    }
  };

  f32x4 acc[8][2];
#pragma unroll
  for (int m = 0; m < 8; ++m)
#pragma unroll
    for (int n = 0; n < 2; ++n) acc[m][n] = (f32x4){0.f, 0.f, 0.f, 0.f};

  stage(0, 0);
  const int NT = K >> 6;
  for (int t = 0; t < NT; ++t) {
    const int cur = t & 1;
    if (t + 1 < NT) stage((t + 1) << 6, cur ^ 1);
    if (t + 1 >= NT) {
      asm volatile("s_waitcnt vmcnt(0)" ::: "memory");   // epilogue drain only
    } else {
      asm volatile("s_waitcnt vmcnt(6)" ::: "memory");   // oldest 6 = buf[cur]
    }
    __builtin_amdgcn_s_barrier();

    const char* Ab = smem + cur * SMHALF;
    const char* Bb = Ab + 32768;
    bf16x8 bfr[2][2];
#pragma unroll
    for (int n = 0; n < 2; ++n)
#pragma unroll
      for (int s = 0; s < 2; ++s) {
        int row = wn * 32 + n * 16 + frow;
        int cb = s * 64 + kgrp * 16;
        bfr[n][s] = *(const bf16x8*)(Bb + row * 128 + (cb ^ ((row & 7) << 4)));
      }
#pragma unroll
    for (int mh = 0; mh < 2; ++mh) {
      bf16x8 af[4][2];
#pragma unroll
      for (int m = 0; m < 4; ++m)
#pragma unroll
        for (int s = 0; s < 2; ++s) {
          int row = wm * 128 + (mh * 4 + m) * 16 + frow;
          int cb = s * 64 + kgrp * 16;
          af[m][s] = *(const bf16x8*)(Ab + row * 128 + (cb ^ ((row & 7) << 4)));
        }
#pragma unroll
      for (int m = 0; m < 4; ++m)
#pragma unroll
        for (int n = 0; n < 2; ++n)
#pragma unroll
          for (int s = 0; s < 2; ++s)
            acc[mh * 4 + m][n] = __builtin_amdgcn_mfma_f32_16x16x32_bf16(
                af[m][s], bfr[n][s], acc[mh * 4 + m][n], 0, 0, 0);
    }
    __builtin_amdgcn_s_barrier();
  }

  const int r0 = bm * 256 + wm * 128;
  const int c0 = bn * 128 + wn * 32;
#pragma unroll
  for (int n = 0; n < 2; ++n) {
    int col = c0 + n * 16 + frow;
    float bv = bias[col];
#pragma unroll
    for (int m = 0; m < 8; ++m)
#pragma unroll
      for (int j = 0; j < 4; ++j) {
        int row = r0 + m * 16 + kgrp * 4 + j;
        float v = acc[m][n][j] + bv;
        if (MODE == 2) {
          v += __bfloat162float(extra[(size_t)row * N + col]);
          ((__hip_bfloat16*)out)[(size_t)row * N + col] = __float2bfloat16(v);
        } else {
          ((float*)out)[(size_t)row * N + col] = v;
        }
      }
  }
}

extern "C" void kernel_launch(void* const* d_in, const int* in_sizes, int n_in,
                              void* d_out, int out_size, void* d_ws, size_t ws_size,
                              hipStream_t stream) {
  (void)in_sizes; (void)n_in; (void)out_size; (void)ws_size;
  const float* x     = (const float*)d_in[0];
  const float* W_in  = (const float*)d_in[1];
  const float* b_in  = (const float*)d_in[2];
  const float* W_hid = (const float*)d_in[3];
  const float* b_hid = (const float*)d_in[4];
  const float* W_fb  = (const float*)d_in[5];
  const float* b_fb  = (const float*)d_in[6];
  const float* W_agg = (const float*)d_in[7];
  const float* b_agg = (const float*)d_in[8];
  const float* W_out = (const float*)d_in[9];
  const float* b_out = (const float*)d_in[10];
  const float* noise = (const float*)d_in[11];

  const int B = B_DIM, H = H_DIM, P = NPATH;
  const int R = B * P;

  size_t off = 0;
  char* base = (char*)d_ws;
  auto take = [&](size_t bytes) -> char* {
    char* r = base + off;
    off = (off + bytes + 255) & ~(size_t)255;
    return r;
  };
  __hip_bfloat16* xb    = (__hip_bfloat16*)take((size_t)B * H * 2);  // reused as `combined`
  __hip_bfloat16* h1b   = (__hip_bfloat16*)take((size_t)B * H * 2);
  __hip_bfloat16* h2b   = (__hip_bfloat16*)take((size_t)B * H * 2);
  __hip_bfloat16* wtin  = (__hip_bfloat16*)take((size_t)H * H * 2);
  __hip_bfloat16* wthid = (__hip_bfloat16*)take((size_t)H * H * 2);
  __hip_bfloat16* wtout = (__hip_bfloat16*)take((size_t)H * H * 2);
  __hip_bfloat16* wtagg = (__hip_bfloat16*)take((size_t)H * P * 2);
  float* ns = (float*)take((size_t)R * 4);
  __hip_bfloat16* eb = (__hip_bfloat16*)take((size_t)R * 2);

  float dt = 1.0f / NSTEP;
  float DI = 0.f;
  for (int j = 0; j < NSTEP; ++j) DI += expf(-0.1f * ((float)j * dt));
  DI *= dt;
  float SQDT = sqrtf(dt);

  prep_kernel<<<11520, 256, 0, stream>>>(x, W_in, W_hid, W_out, W_agg,
                                         xb, wtin, wthid, wtout, wtagg);

  // trunk stages: 3:1 group interleave (512 GEMM + 256 noise blocks, grid 768)
  stage_kernel<<<768, 256, 0, stream>>>(xb, wtin, b_in, h1b, noise, ns, 0, R / 2);
  stage_kernel<<<768, 256, 0, stream>>>(h1b, wthid, b_hid, h2b, noise, ns, R / 2, R - R / 2);
  fb_end_kernel<<<B / 4, 256, 0, stream>>>(h2b, W_fb, b_fb, ns, eb, DI, SQDT);
  // bicep: eb @ wtagg^T + b_agg + h2 -> xb (combined), K=256
  gemm8<2><<<256, 512, 0, stream>>>(eb, wtagg, b_agg, h2b, xb, H, P, 256);
  // final: combined @ W_out^T + b_out -> fp32 d_out, K=1024
  gemm8<3><<<256, 512, 0, stream>>>(xb, wtout, b_out, nullptr, d_out, H, H, 256);
}

// Round 20
// 196.807 us; speedup vs baseline: 1.1850x; 1.1850x over previous
//
#include <hip/hip_runtime.h>
#include <hip/hip_bf16.h>
#include <math.h>

typedef short bf16x8 __attribute__((ext_vector_type(8)));
typedef float f32x4 __attribute__((ext_vector_type(4)));
typedef unsigned int u32;

#define B_DIM 8192
#define H_DIM 1024
#define NPATH 256
#define NSTEP 50

__device__ __forceinline__ void gld_lds16(const void* g, void* lds) {
  __builtin_amdgcn_global_load_lds(
      (const __attribute__((address_space(1))) u32*)g,
      (__attribute__((address_space(3))) u32*)lds, 16, 0, 0);
}

__device__ __forceinline__ void cast4(const float* in, __hip_bfloat16* out, int i) {
  float4 v = ((const float4*)in)[i];
  union { __hip_bfloat16 h[4]; short4 s; } u;
  u.h[0] = __float2bfloat16(v.x);
  u.h[1] = __float2bfloat16(v.y);
  u.h[2] = __float2bfloat16(v.z);
  u.h[3] = __float2bfloat16(v.w);
  ((short4*)out)[i] = u.s;
}

// ---------------- fused prep: weight transposes only (x read fp32 in stage1) ---
// [0,3072) transpose W_in/W_hid/W_out ; [3072,3328) W_agg^T
__global__ __launch_bounds__(256) void prep_kernel(
    const float* __restrict__ W_in, const float* __restrict__ W_hid,
    const float* __restrict__ W_out, const float* __restrict__ W_agg,
    __hip_bfloat16* __restrict__ wtin, __hip_bfloat16* __restrict__ wthid,
    __hip_bfloat16* __restrict__ wtout, __hip_bfloat16* __restrict__ wtagg) {
  __shared__ float t[32][33];
  int bid = blockIdx.x, tid = threadIdx.x;
  int job = bid;
  const float* W; __hip_bfloat16* Wt; int R, C;
  if (job < 1024)      { W = W_in;  Wt = wtin;  R = 1024; C = 1024; }
  else if (job < 2048) { W = W_hid; Wt = wthid; R = 1024; C = 1024; job -= 1024; }
  else if (job < 3072) { W = W_out; Wt = wtout; R = 1024; C = 1024; job -= 2048; }
  else                 { W = W_agg; Wt = wtagg; R = 256;  C = 1024; job -= 3072; }
  int nTx = C / 32;
  int tX = job % nTx, tY = job / nTx;
  int tx = tid & 31, r4 = tid >> 5;
#pragma unroll
  for (int i = 0; i < 4; ++i) {
    int ty = r4 * 4 + i;
    t[ty][tx] = W[(size_t)(tY * 32 + ty) * C + tX * 32 + tx];
  }
  __syncthreads();
#pragma unroll
  for (int i = 0; i < 4; ++i) {
    int ty = r4 * 4 + i;
    Wt[(size_t)(tX * 32 + ty) * R + tY * 32 + tx] = __float2bfloat16(t[tx][ty]);
  }
}

// ------------- fused feedback + endpoints: per block = 4 batch rows -------------
// sb holds bf16(SQDT * noise-rowsum); eb = bf16(fb*DI + sb)
__global__ __launch_bounds__(256) void fb_end_kernel(
    const __hip_bfloat16* __restrict__ h2b, const float* __restrict__ Wfb,
    const float* __restrict__ bfb, const __hip_bfloat16* __restrict__ sb,
    __hip_bfloat16* __restrict__ eb, float DI) {
  __shared__ float fv[4];
  int wid = threadIdx.x >> 6, lane = threadIdx.x & 63;
  int row = blockIdx.x * 4 + wid;
  const __hip_bfloat16* hrow = h2b + (size_t)row * H_DIM;
  float s = 0.f;
#pragma unroll
  for (int i = lane; i < H_DIM; i += 64) s += __bfloat162float(hrow[i]) * Wfb[i];
#pragma unroll
  for (int off = 32; off > 0; off >>= 1) s += __shfl_down(s, off);
  if (lane == 0) fv[wid] = 1.0f / (1.0f + expf(-(s + bfb[0])));
  __syncthreads();
#pragma unroll
  for (int w = 0; w < 4; ++w) {
    size_t i = (size_t)(blockIdx.x * 4 + w) * NPATH + threadIdx.x;
    eb[i] = __float2bfloat16(fv[w] * DI + __bfloat162float(sb[i]));
  }
}

// -------- trunk stage: R17 group-of-8 interleave (best measured structure) -----
// AF32: A operand read directly as fp32 (x) via reg-staged cvt + ds_write_b128
// (deletes the 48MB x-cast from prep's serial path; B stays gld_lds bf16).
// Noise blocks write sb = bf16(SQDT * rowsum) directly.
template <bool AF32>
__global__ __launch_bounds__(256) void stage_kernel(
    const __hip_bfloat16* __restrict__ A, const float* __restrict__ Af,
    const __hip_bfloat16* __restrict__ Bt,
    const float* __restrict__ bias, __hip_bfloat16* __restrict__ out,
    const float* __restrict__ noise, __hip_bfloat16* __restrict__ sb,
    int rowStart, int rowCount, float SQDT) {
  __shared__ __hip_bfloat16 As[128 * 64];
  __shared__ __hip_bfloat16 Bs[128 * 64];
  const int bid = blockIdx.x;
  const int group = bid >> 3, l = bid & 7;
  if ((group & 1) == 0) {
    int j = (group >> 1) * 8 + l;  // 512 noise blocks, grid-stride
    for (int r = j * 256 + threadIdx.x; r < rowCount; r += 512 * 256) {
      const float2* p = (const float2*)(noise + (size_t)(rowStart + r) * NSTEP);
      float s = 0.f;
#pragma unroll
      for (int i = 0; i < NSTEP / 2; ++i) { float2 v = p[i]; s += v.x + v.y; }
      sb[rowStart + r] = __float2bfloat16(SQDT * s);
    }
    return;
  }
  const int g_i = group >> 1;                  // 0..63
  const int bm = (g_i >> 3) * 8 + l;           // XCD-local A panels
  const int bn = g_i & 7;
  const int tid = threadIdx.x;
  const int lane = tid & 63, wid = tid >> 6;
  const int wr = wid >> 1, wc = wid & 1;
  const int frow = lane & 15, kgrp = lane >> 4;

  f32x4 acc[4][4];
#pragma unroll
  for (int m = 0; m < 4; ++m)
#pragma unroll
    for (int n = 0; n < 4; ++n) acc[m][n] = (f32x4){0.f, 0.f, 0.f, 0.f};

  for (int kt = 0; kt < H_DIM; kt += 64) {
#pragma unroll
    for (int r = 0; r < 4; ++r) {
      int c = r * 256 + tid;
      int row = c >> 3, cc = c & 7;
      if (AF32) {
        // reg-staged fp32 -> bf16: 2x float4 (32B, coalesced 256B/row) -> ds_write_b128
        const float* src = Af + (size_t)(bm * 128 + row) * H_DIM + kt + cc * 8;
        float4 v0 = *(const float4*)src;
        float4 v1 = *(const float4*)(src + 4);
        union { __hip_bfloat16 h[8]; bf16x8 v; } u;
        u.h[0] = __float2bfloat16(v0.x); u.h[1] = __float2bfloat16(v0.y);
        u.h[2] = __float2bfloat16(v0.z); u.h[3] = __float2bfloat16(v0.w);
        u.h[4] = __float2bfloat16(v1.x); u.h[5] = __float2bfloat16(v1.y);
        u.h[6] = __float2bfloat16(v1.z); u.h[7] = __float2bfloat16(v1.w);
        *(bf16x8*)((char*)As + c * 16) = u.v;
      } else {
        gld_lds16((const char*)(A + (size_t)(bm * 128 + row) * H_DIM + kt) + cc * 16,
                  (char*)As + c * 16);
      }
      gld_lds16((const char*)(Bt + (size_t)(bn * 128 + row) * H_DIM + kt) + cc * 16,
                (char*)Bs + c * 16);
    }
    __syncthreads();
#pragma unroll
    for (int kk = 0; kk < 64; kk += 32) {
      bf16x8 af[4], bfr[4];
#pragma unroll
      for (int m = 0; m < 4; ++m)
        af[m] = *(const bf16x8*)(As + (wr * 64 + m * 16 + frow) * 64 + kk + kgrp * 8);
#pragma unroll
      for (int n = 0; n < 4; ++n)
        bfr[n] = *(const bf16x8*)(Bs + (wc * 64 + n * 16 + frow) * 64 + kk + kgrp * 8);
#pragma unroll
      for (int m = 0; m < 4; ++m)
#pragma unroll
        for (int n = 0; n < 4; ++n)
          acc[m][n] = __builtin_amdgcn_mfma_f32_16x16x32_bf16(af[m], bfr[n], acc[m][n], 0, 0, 0);
    }
    __syncthreads();
  }

  const int r0 = bm * 128 + wr * 64;
  const int c0 = bn * 128 + wc * 64;
#pragma unroll
  for (int n = 0; n < 4; ++n) {
    int col = c0 + n * 16 + frow;
    float bv = bias[col];
#pragma unroll
    for (int m = 0; m < 4; ++m)
#pragma unroll
      for (int j = 0; j < 4; ++j) {
        int row = r0 + m * 16 + kgrp * 4 + j;
        out[(size_t)row * H_DIM + col] = __float2bfloat16(fmaxf(acc[m][n][j] + bv, 0.f));
      }
  }
}

// ---------------- 256x128-tile core for bicep/final (counted-vmcnt dbuf) -------
// BM=256, BN=128, BK=64, 8 waves, pre-swizzled-source T2 + XCD bijective remap.
// MODE 2: +bias+extra->bf16 ; MODE 3: fp32.
template <int MODE>
__global__ __launch_bounds__(512) void gemm8(
    const __hip_bfloat16* __restrict__ A, const __hip_bfloat16* __restrict__ Bt,
    const float* __restrict__ bias, const __hip_bfloat16* __restrict__ extra,
    void* __restrict__ out, int N, int K, int nGemm) {
  constexpr int SMHALF = (256 + 128) * 64 * 2;
  __shared__ char smem[2 * SMHALF];

  const int tid = threadIdx.x;
  const int lane = tid & 63, wid = tid >> 6;
  const int wm = wid >> 2, wn = wid & 3;
  const int frow = lane & 15, kgrp = lane >> 4;
  const int cpx = nGemm >> 3;
  const int gb = (blockIdx.x & 7) * cpx + (blockIdx.x >> 3);  // XCD remap
  const int gx = N / 128;
  const int bm = gb / gx, bn = gb % gx;
  const size_t arow0 = (size_t)(bm * 256) * K;
  const size_t brow0 = (size_t)(bn * 128) * K;

  auto stage = [&](int kt, int d) {
    char* dst = smem + d * SMHALF;
#pragma unroll
    for (int j = 0; j < 6; ++j) {
      int c = j * 512 + tid;
      if (j < 4) {  // A tile: 256x64
        int row = c >> 3, cb = (c & 7) * 16;
        int col = (cb ^ ((row & 7) << 4)) >> 1;
        gld_lds16((const void*)(A + arow0 + (size_t)row * K + kt + col), dst + c * 16);
      } else {      // B tile: 128x64
        int cB = c - 2048;
        int row = cB >> 3, cb = (cB & 7) * 16;
        int col = (cb ^ ((row & 7) << 4)) >> 1;
        gld_lds16((const void*)(Bt + brow0 + (size_t)row * K + kt + col), dst + 32768 + cB * 16);
      }
    }
  };

  f32x4 acc[8][2];
#pragma unroll
  for (int m = 0; m < 8; ++m)
#pragma unroll
    for (int n = 0; n < 2; ++n) acc[m][n] = (f32x4){0.f, 0.f, 0.f, 0.f};

  stage(0, 0);
  const int NT = K >> 6;
  for (int t = 0; t < NT; ++t) {
    const int cur = t & 1;
    if (t + 1 < NT) stage((t + 1) << 6, cur ^ 1);
    if (t + 1 >= NT) {
      asm volatile("s_waitcnt vmcnt(0)" ::: "memory");   // epilogue drain only
    } else {
      asm volatile("s_waitcnt vmcnt(6)" ::: "memory");   // oldest 6 = buf[cur]
    }
    __builtin_amdgcn_s_barrier();

    const char* Ab = smem + cur * SMHALF;
    const char* Bb = Ab + 32768;
    bf16x8 bfr[2][2];
#pragma unroll
    for (int n = 0; n < 2; ++n)
#pragma unroll
      for (int s = 0; s < 2; ++s) {
        int row = wn * 32 + n * 16 + frow;
        int cb = s * 64 + kgrp * 16;
        bfr[n][s] = *(const bf16x8*)(Bb + row * 128 + (cb ^ ((row & 7) << 4)));
      }
#pragma unroll
    for (int mh = 0; mh < 2; ++mh) {
      bf16x8 af[4][2];
#pragma unroll
      for (int m = 0; m < 4; ++m)
#pragma unroll
        for (int s = 0; s < 2; ++s) {
          int row = wm * 128 + (mh * 4 + m) * 16 + frow;
          int cb = s * 64 + kgrp * 16;
          af[m][s] = *(const bf16x8*)(Ab + row * 128 + (cb ^ ((row & 7) << 4)));
        }
#pragma unroll
      for (int m = 0; m < 4; ++m)
#pragma unroll
        for (int n = 0; n < 2; ++n)
#pragma unroll
          for (int s = 0; s < 2; ++s)
            acc[mh * 4 + m][n] = __builtin_amdgcn_mfma_f32_16x16x32_bf16(
                af[m][s], bfr[n][s], acc[mh * 4 + m][n], 0, 0, 0);
    }
    __builtin_amdgcn_s_barrier();
  }

  const int r0 = bm * 256 + wm * 128;
  const int c0 = bn * 128 + wn * 32;
#pragma unroll
  for (int n = 0; n < 2; ++n) {
    int col = c0 + n * 16 + frow;
    float bv = bias[col];
#pragma unroll
    for (int m = 0; m < 8; ++m)
#pragma unroll
      for (int j = 0; j < 4; ++j) {
        int row = r0 + m * 16 + kgrp * 4 + j;
        float v = acc[m][n][j] + bv;
        if (MODE == 2) {
          v += __bfloat162float(extra[(size_t)row * N + col]);
          ((__hip_bfloat16*)out)[(size_t)row * N + col] = __float2bfloat16(v);
        } else {
          ((float*)out)[(size_t)row * N + col] = v;
        }
      }
  }
}

extern "C" void kernel_launch(void* const* d_in, const int* in_sizes, int n_in,
                              void* d_out, int out_size, void* d_ws, size_t ws_size,
                              hipStream_t stream) {
  (void)in_sizes; (void)n_in; (void)out_size; (void)ws_size;
  const float* x     = (const float*)d_in[0];
  const float* W_in  = (const float*)d_in[1];
  const float* b_in  = (const float*)d_in[2];
  const float* W_hid = (const float*)d_in[3];
  const float* b_hid = (const float*)d_in[4];
  const float* W_fb  = (const float*)d_in[5];
  const float* b_fb  = (const float*)d_in[6];
  const float* W_agg = (const float*)d_in[7];
  const float* b_agg = (const float*)d_in[8];
  const float* W_out = (const float*)d_in[9];
  const float* b_out = (const float*)d_in[10];
  const float* noise = (const float*)d_in[11];

  const int B = B_DIM, H = H_DIM, P = NPATH;
  const int R = B * P;

  size_t off = 0;
  char* base = (char*)d_ws;
  auto take = [&](size_t bytes) -> char* {
    char* r = base + off;
    off = (off + bytes + 255) & ~(size_t)255;
    return r;
  };
  __hip_bfloat16* h1b   = (__hip_bfloat16*)take((size_t)B * H * 2);
  __hip_bfloat16* h2b   = (__hip_bfloat16*)take((size_t)B * H * 2);
  __hip_bfloat16* comb  = (__hip_bfloat16*)take((size_t)B * H * 2);
  __hip_bfloat16* wtin  = (__hip_bfloat16*)take((size_t)H * H * 2);
  __hip_bfloat16* wthid = (__hip_bfloat16*)take((size_t)H * H * 2);
  __hip_bfloat16* wtout = (__hip_bfloat16*)take((size_t)H * H * 2);
  __hip_bfloat16* wtagg = (__hip_bfloat16*)take((size_t)H * P * 2);
  __hip_bfloat16* sb    = (__hip_bfloat16*)take((size_t)R * 2);
  __hip_bfloat16* eb    = (__hip_bfloat16*)take((size_t)R * 2);

  float dt = 1.0f / NSTEP;
  float DI = 0.f;
  for (int j = 0; j < NSTEP; ++j) DI += expf(-0.1f * ((float)j * dt));
  DI *= dt;
  float SQDT = sqrtf(dt);

  prep_kernel<<<3328, 256, 0, stream>>>(W_in, W_hid, W_out, W_agg,
                                        wtin, wthid, wtout, wtagg);

  // trunk stages: R17 group-of-8 interleave; stage1 reads x as fp32 directly
  stage_kernel<true><<<1024, 256, 0, stream>>>(nullptr, x, wtin, b_in, h1b,
                                               noise, sb, 0, R / 2, SQDT);
  stage_kernel<false><<<1024, 256, 0, stream>>>(h1b, nullptr, wthid, b_hid, h2b,
                                                noise, sb, R / 2, R - R / 2, SQDT);
  fb_end_kernel<<<B / 4, 256, 0, stream>>>(h2b, W_fb, b_fb, sb, eb, DI);
  // bicep: eb @ wtagg^T + b_agg + h2 -> comb, K=256
  gemm8<2><<<256, 512, 0, stream>>>(eb, wtagg, b_agg, h2b, comb, H, P, 256);
  // final: comb @ W_out^T + b_out -> fp32 d_out, K=1024
  gemm8<3><<<256, 512, 0, stream>>>(comb, wtout, b_out, nullptr, d_out, H, H, 256);
}

// Round 21
// 188.007 us; speedup vs baseline: 1.2405x; 1.0468x over previous
//
#include <hip/hip_runtime.h>
#include <hip/hip_bf16.h>
#include <math.h>

typedef short bf16x8 __attribute__((ext_vector_type(8)));
typedef float f32x4 __attribute__((ext_vector_type(4)));
typedef unsigned int u32;

#define B_DIM 8192
#define H_DIM 1024
#define NPATH 256
#define NSTEP 50

__device__ __forceinline__ void gld_lds16(const void* g, void* lds) {
  __builtin_amdgcn_global_load_lds(
      (const __attribute__((address_space(1))) u32*)g,
      (__attribute__((address_space(3))) u32*)lds, 16, 0, 0);
}

__device__ __forceinline__ void cast4(const float* in, __hip_bfloat16* out, int i) {
  float4 v = ((const float4*)in)[i];
  union { __hip_bfloat16 h[4]; short4 s; } u;
  u.h[0] = __float2bfloat16(v.x);
  u.h[1] = __float2bfloat16(v.y);
  u.h[2] = __float2bfloat16(v.z);
  u.h[3] = __float2bfloat16(v.w);
  ((short4*)out)[i] = u.s;
}

// ---------------- fused prep: pure data movement ----------------
// [0,8192) cast x ; [8192,11264) transpose W_in/W_hid/W_out ; [11264,11520) W_agg^T
__global__ __launch_bounds__(256) void prep_kernel(
    const float* __restrict__ x, const float* __restrict__ W_in,
    const float* __restrict__ W_hid, const float* __restrict__ W_out,
    const float* __restrict__ W_agg,
    __hip_bfloat16* __restrict__ xb, __hip_bfloat16* __restrict__ wtin,
    __hip_bfloat16* __restrict__ wthid, __hip_bfloat16* __restrict__ wtout,
    __hip_bfloat16* __restrict__ wtagg) {
  __shared__ float t[32][33];
  int bid = blockIdx.x, tid = threadIdx.x;
  if (bid < 8192) {
    cast4(x, xb, bid * 256 + tid);
    return;
  }
  int job = bid - 8192;
  const float* W; __hip_bfloat16* Wt; int R, C;
  if (job < 1024)      { W = W_in;  Wt = wtin;  R = 1024; C = 1024; }
  else if (job < 2048) { W = W_hid; Wt = wthid; R = 1024; C = 1024; job -= 1024; }
  else if (job < 3072) { W = W_out; Wt = wtout; R = 1024; C = 1024; job -= 2048; }
  else                 { W = W_agg; Wt = wtagg; R = 256;  C = 1024; job -= 3072; }
  int nTx = C / 32;
  int tX = job % nTx, tY = job / nTx;
  int tx = tid & 31, r4 = tid >> 5;
#pragma unroll
  for (int i = 0; i < 4; ++i) {
    int ty = r4 * 4 + i;
    t[ty][tx] = W[(size_t)(tY * 32 + ty) * C + tX * 32 + tx];
  }
  __syncthreads();
#pragma unroll
  for (int i = 0; i < 4; ++i) {
    int ty = r4 * 4 + i;
    Wt[(size_t)(tX * 32 + ty) * R + tY * 32 + tx] = __float2bfloat16(t[tx][ty]);
  }
}

// ------------- fused feedback + endpoints: per block = 4 batch rows -------------
__global__ __launch_bounds__(256) void fb_end_kernel(
    const __hip_bfloat16* __restrict__ h2b, const float* __restrict__ Wfb,
    const float* __restrict__ bfb, const float* __restrict__ ns,
    __hip_bfloat16* __restrict__ eb, float DI, float SQDT) {
  __shared__ float fv[4];
  int wid = threadIdx.x >> 6, lane = threadIdx.x & 63;
  int row = blockIdx.x * 4 + wid;
  const __hip_bfloat16* hrow = h2b + (size_t)row * H_DIM;
  float s = 0.f;
#pragma unroll
  for (int i = lane; i < H_DIM; i += 64) s += __bfloat162float(hrow[i]) * Wfb[i];
#pragma unroll
  for (int off = 32; off > 0; off >>= 1) s += __shfl_down(s, off);
  if (lane == 0) fv[wid] = 1.0f / (1.0f + expf(-(s + bfb[0])));
  __syncthreads();
#pragma unroll
  for (int w = 0; w < 4; ++w) {
    size_t i = (size_t)(blockIdx.x * 4 + w) * NPATH + threadIdx.x;
    eb[i] = __float2bfloat16(fv[w] * DI + SQDT * ns[i]);
  }
}

// -------- trunk stage: GROUP-OF-8 role interleave + XCD-local tile remap -------
// grid 1024 = 128 groups of 8. Even group -> noise, odd group -> GEMM. Under the
// bid%8->XCD placement heuristic every XCD gets alternating roles (every CU:
// ~2 GEMM + 2 noise blocks = m114 MFMA/HBM overlap, no barrier coupling); under
// linear fill it degrades to R9's fine-grained partition.
// GEMM tile remap for XCD A-locality: l = bid&7 (presumed XCD), g_i = group>>1;
// bm = (g_i>>3)*8 + l, bn = g_i&7 -> XCD l re-reads each of its 8 A-panels 8x
// from its own L2.
__global__ __launch_bounds__(256) void stage_kernel(
    const __hip_bfloat16* __restrict__ A, const __hip_bfloat16* __restrict__ Bt,
    const float* __restrict__ bias, __hip_bfloat16* __restrict__ out,
    const float* __restrict__ noise, float* __restrict__ ns,
    int rowStart, int rowCount) {
  __shared__ __hip_bfloat16 As[128 * 64];
  __shared__ __hip_bfloat16 Bs[128 * 64];
  const int bid = blockIdx.x;
  const int group = bid >> 3, l = bid & 7;
  if ((group & 1) == 0) {
    int j = (group >> 1) * 8 + l;  // 512 noise blocks, grid-stride
    for (int r = j * 256 + threadIdx.x; r < rowCount; r += 512 * 256) {
      const float2* p = (const float2*)(noise + (size_t)(rowStart + r) * NSTEP);
      float s = 0.f;
#pragma unroll
      for (int i = 0; i < NSTEP / 2; ++i) { float2 v = p[i]; s += v.x + v.y; }
      ns[rowStart + r] = s;
    }
    return;
  }
  const int g_i = group >> 1;                  // 0..63
  const int bm = (g_i >> 3) * 8 + l;           // XCD-local A panels
  const int bn = g_i & 7;
  const int tid = threadIdx.x;
  const int lane = tid & 63, wid = tid >> 6;
  const int wr = wid >> 1, wc = wid & 1;
  const int frow = lane & 15, kgrp = lane >> 4;

  f32x4 acc[4][4];
#pragma unroll
  for (int m = 0; m < 4; ++m)
#pragma unroll
    for (int n = 0; n < 4; ++n) acc[m][n] = (f32x4){0.f, 0.f, 0.f, 0.f};

  for (int kt = 0; kt < H_DIM; kt += 64) {
#pragma unroll
    for (int r = 0; r < 4; ++r) {
      int c = r * 256 + tid;
      int row = c >> 3, cc = c & 7;
      gld_lds16((const char*)(A + (size_t)(bm * 128 + row) * H_DIM + kt) + cc * 16,
                (char*)As + c * 16);
      gld_lds16((const char*)(Bt + (size_t)(bn * 128 + row) * H_DIM + kt) + cc * 16,
                (char*)Bs + c * 16);
    }
    __syncthreads();
#pragma unroll
    for (int kk = 0; kk < 64; kk += 32) {
      bf16x8 af[4], bfr[4];
#pragma unroll
      for (int m = 0; m < 4; ++m)
        af[m] = *(const bf16x8*)(As + (wr * 64 + m * 16 + frow) * 64 + kk + kgrp * 8);
#pragma unroll
      for (int n = 0; n < 4; ++n)
        bfr[n] = *(const bf16x8*)(Bs + (wc * 64 + n * 16 + frow) * 64 + kk + kgrp * 8);
#pragma unroll
      for (int m = 0; m < 4; ++m)
#pragma unroll
        for (int n = 0; n < 4; ++n)
          acc[m][n] = __builtin_amdgcn_mfma_f32_16x16x32_bf16(af[m], bfr[n], acc[m][n], 0, 0, 0);
    }
    __syncthreads();
  }

  const int r0 = bm * 128 + wr * 64;
  const int c0 = bn * 128 + wc * 64;
#pragma unroll
  for (int n = 0; n < 4; ++n) {
    int col = c0 + n * 16 + frow;
    float bv = bias[col];
#pragma unroll
    for (int m = 0; m < 4; ++m)
#pragma unroll
      for (int j = 0; j < 4; ++j) {
        int row = r0 + m * 16 + kgrp * 4 + j;
        out[(size_t)row * H_DIM + col] = __float2bfloat16(fmaxf(acc[m][n][j] + bv, 0.f));
      }
  }
}

// ---------------- 256x128-tile core for bicep/final (counted-vmcnt dbuf) -------
// BM=256, BN=128, BK=64, 8 waves, pre-swizzled-source T2 + XCD bijective remap.
// t==0 waits vmcnt(6) (stage(0) only), keeping the t=1 prefetch in flight.
// MODE 2: +bias+extra->bf16 ; MODE 3: fp32.
template <int MODE>
__global__ __launch_bounds__(512) void gemm8(
    const __hip_bfloat16* __restrict__ A, const __hip_bfloat16* __restrict__ Bt,
    const float* __restrict__ bias, const __hip_bfloat16* __restrict__ extra,
    void* __restrict__ out, int N, int K, int nGemm) {
  constexpr int SMHALF = (256 + 128) * 64 * 2;
  __shared__ char smem[2 * SMHALF];

  const int tid = threadIdx.x;
  const int lane = tid & 63, wid = tid >> 6;
  const int wm = wid >> 2, wn = wid & 3;
  const int frow = lane & 15, kgrp = lane >> 4;
  const int cpx = nGemm >> 3;
  const int gb = (blockIdx.x & 7) * cpx + (blockIdx.x >> 3);  // XCD remap
  const int gx = N / 128;
  const int bm = gb / gx, bn = gb % gx;
  const size_t arow0 = (size_t)(bm * 256) * K;
  const size_t brow0 = (size_t)(bn * 128) * K;

  auto stage = [&](int kt, int d) {
    char* dst = smem + d * SMHALF;
#pragma unroll
    for (int j = 0; j < 6; ++j) {
      int c = j * 512 + tid;
      if (j < 4) {  // A tile: 256x64
        int row = c >> 3, cb = (c & 7) * 16;
        int col = (cb ^ ((row & 7) << 4)) >> 1;
        gld_lds16((const void*)(A + arow0 + (size_t)row * K + kt + col), dst + c * 16);
      } else {      // B tile: 128x64
        int cB = c - 2048;
        int row = cB >> 3, cb = (cB & 7) * 16;
        int col = (cb ^ ((row & 7) << 4)) >> 1;
        gld_lds16((const void*)(Bt + brow0 + (size_t)row * K + kt + col), dst + 32768 + cB * 16);
      }
    }
  };

  f32x4 acc[8][2];
#pragma unroll
  for (int m = 0; m < 8; ++m)
#pragma unroll
    for (int n = 0; n < 2; ++n) acc[m][n] = (f32x4){0.f, 0.f, 0.f, 0.f};

  stage(0, 0);
  const int NT = K >> 6;
  for (int t = 0; t < NT; ++t) {
    const int cur = t & 1;
    if (t + 1 < NT) stage((t + 1) << 6, cur ^ 1);
    if (t + 1 >= NT) {
      asm volatile("s_waitcnt vmcnt(0)" ::: "memory");   // epilogue drain only
    } else {
      asm volatile("s_waitcnt vmcnt(6)" ::: "memory");   // oldest 6 = buf[cur]
    }
    __builtin_amdgcn_s_barrier();

    const char* Ab = smem + cur * SMHALF;
    const char* Bb = Ab + 32768;
    bf16x8 bfr[2][2];
#pragma unroll
    for (int n = 0; n < 2; ++n)
#pragma unroll
      for (int s = 0; s < 2; ++s) {
        int row = wn * 32 + n * 16 + frow;
        int cb = s * 64 + kgrp * 16;
        bfr[n][s] = *(const bf16x8*)(Bb + row * 128 + (cb ^ ((row & 7) << 4)));
      }
#pragma unroll
    for (int mh = 0; mh < 2; ++mh) {
      bf16x8 af[4][2];
#pragma unroll
      for (int m = 0; m < 4; ++m)
#pragma unroll
        for (int s = 0; s < 2; ++s) {
          int row = wm * 128 + (mh * 4 + m) * 16 + frow;
          int cb = s * 64 + kgrp * 16;
          af[m][s] = *(const bf16x8*)(Ab + row * 128 + (cb ^ ((row & 7) << 4)));
        }
#pragma unroll
      for (int m = 0; m < 4; ++m)
#pragma unroll
        for (int n = 0; n < 2; ++n)
#pragma unroll
          for (int s = 0; s < 2; ++s)
            acc[mh * 4 + m][n] = __builtin_amdgcn_mfma_f32_16x16x32_bf16(
                af[m][s], bfr[n][s], acc[mh * 4 + m][n], 0, 0, 0);
    }
    __builtin_amdgcn_s_barrier();
  }

  const int r0 = bm * 256 + wm * 128;
  const int c0 = bn * 128 + wn * 32;
#pragma unroll
  for (int n = 0; n < 2; ++n) {
    int col = c0 + n * 16 + frow;
    float bv = bias[col];
#pragma unroll
    for (int m = 0; m < 8; ++m)
#pragma unroll
      for (int j = 0; j < 4; ++j) {
        int row = r0 + m * 16 + kgrp * 4 + j;
        float v = acc[m][n][j] + bv;
        if (MODE == 2) {
          v += __bfloat162float(extra[(size_t)row * N + col]);
          ((__hip_bfloat16*)out)[(size_t)row * N + col] = __float2bfloat16(v);
        } else {
          ((float*)out)[(size_t)row * N + col] = v;
        }
      }
  }
}

extern "C" void kernel_launch(void* const* d_in, const int* in_sizes, int n_in,
                              void* d_out, int out_size, void* d_ws, size_t ws_size,
                              hipStream_t stream) {
  (void)in_sizes; (void)n_in; (void)out_size; (void)ws_size;
  const float* x     = (const float*)d_in[0];
  const float* W_in  = (const float*)d_in[1];
  const float* b_in  = (const float*)d_in[2];
  const float* W_hid = (const float*)d_in[3];
  const float* b_hid = (const float*)d_in[4];
  const float* W_fb  = (const float*)d_in[5];
  const float* b_fb  = (const float*)d_in[6];
  const float* W_agg = (const float*)d_in[7];
  const float* b_agg = (const float*)d_in[8];
  const float* W_out = (const float*)d_in[9];
  const float* b_out = (const float*)d_in[10];
  const float* noise = (const float*)d_in[11];

  const int B = B_DIM, H = H_DIM, P = NPATH;
  const int R = B * P;

  size_t off = 0;
  char* base = (char*)d_ws;
  auto take = [&](size_t bytes) -> char* {
    char* r = base + off;
    off = (off + bytes + 255) & ~(size_t)255;
    return r;
  };
  __hip_bfloat16* xb    = (__hip_bfloat16*)take((size_t)B * H * 2);  // reused as `combined`
  __hip_bfloat16* h1b   = (__hip_bfloat16*)take((size_t)B * H * 2);
  __hip_bfloat16* h2b   = (__hip_bfloat16*)take((size_t)B * H * 2);
  __hip_bfloat16* wtin  = (__hip_bfloat16*)take((size_t)H * H * 2);
  __hip_bfloat16* wthid = (__hip_bfloat16*)take((size_t)H * H * 2);
  __hip_bfloat16* wtout = (__hip_bfloat16*)take((size_t)H * H * 2);
  __hip_bfloat16* wtagg = (__hip_bfloat16*)take((size_t)H * P * 2);
  float* ns = (float*)take((size_t)R * 4);
  __hip_bfloat16* eb = (__hip_bfloat16*)take((size_t)R * 2);

  float dt = 1.0f / NSTEP;
  float DI = 0.f;
  for (int j = 0; j < NSTEP; ++j) DI += expf(-0.1f * ((float)j * dt));
  DI *= dt;
  float SQDT = sqrtf(dt);

  prep_kernel<<<11520, 256, 0, stream>>>(x, W_in, W_hid, W_out, W_agg,
                                         xb, wtin, wthid, wtout, wtagg);

  // trunk stages: group-of-8 role interleave (512 GEMM + 512 noise blocks)
  stage_kernel<<<1024, 256, 0, stream>>>(xb, wtin, b_in, h1b, noise, ns, 0, R / 2);
  stage_kernel<<<1024, 256, 0, stream>>>(h1b, wthid, b_hid, h2b, noise, ns, R / 2, R - R / 2);
  fb_end_kernel<<<B / 4, 256, 0, stream>>>(h2b, W_fb, b_fb, ns, eb, DI, SQDT);
  // bicep: eb @ wtagg^T + b_agg + h2 -> xb (combined), K=256
  gemm8<2><<<256, 512, 0, stream>>>(eb, wtagg, b_agg, h2b, xb, H, P, 256);
  // final: combined @ W_out^T + b_out -> fp32 d_out, K=1024
  gemm8<3><<<256, 512, 0, stream>>>(xb, wtout, b_out, nullptr, d_out, H, H, 256);
}